// Round 3
// baseline (723.335 us; speedup 1.0000x reference)
//
#include <hip/hip_runtime.h>

#define NA      286   // atoms
#define CIN     23
#define NKH     100   // radial hidden width
#define NKP     50    // k-pairs
#define BATCH   32
#define NB_PAD  320
#define TB      64
#define ATILE   12    // a's per block (3 per wave, 4 waves)
#define APW     3
#define NTILE_A 24
#define NTILE_B 5
#define KQ_N    5     // prep kp-groups
#define KQ_SZ   10    // kp per prep block
#define NGRP    (BATCH * NTILE_B)               // 160 (z,bT) groups
#define ZG      8                               // z's per tail pass

#define Y0F      0.28209479177387814f   // 1/(2 sqrt(pi))
#define RSQRT_N  0.05913123960994873f   // 1/sqrt(286)

typedef _Float16 h2v __attribute__((ext_vector_type(2)));
union F4H { float4 f; h2v h[4]; };

__device__ __forceinline__ h2v h2_splat(float x) {
    _Float16 v = (_Float16)x;
    h2v r; r.x = v; r.y = v; return r;
}
__device__ __forceinline__ h2v h2_pack(float a, float b) {
    h2v r; r.x = (_Float16)a; r.y = (_Float16)b; return r;
}
__device__ __forceinline__ h2v h2_fma(h2v a, h2v b, h2v c) {
#if __has_builtin(__builtin_elementwise_fma)
    return __builtin_elementwise_fma(a, b, c);
#else
    return a * b + c;
#endif
}
__device__ __forceinline__ h2v h2_max0(h2v a) {
    h2v z; z.x = (_Float16)0.f; z.y = (_Float16)0.f;
#if __has_builtin(__builtin_elementwise_max)
    return __builtin_elementwise_max(a, z);
#else
    h2v r; r.x = a.x > z.x ? a.x : z.x; r.y = a.y > z.y ? a.y : z.y; return r;
#endif
}
__device__ __forceinline__ float fdot2f(h2v a, h2v b, float c) {
#if __has_builtin(__builtin_amdgcn_fdot2)
    return __builtin_amdgcn_fdot2(a, b, c, false);
#else
    return c + (float)a.x * (float)b.x + (float)a.y * (float)b.y;
#endif
}

// cos((pi/2)*x) for |x| <= 1; |err| <= ~3e-5
__device__ __forceinline__ float cos_half_pi(float x) {
    float t = 1.5707963267948966f * x;
    float w = t * t;
    return 1.f + w * (-0.5f + w * (4.16666667e-2f + w * (-1.38888889e-3f
               + w * 2.48015873e-5f)));
}

// ---------------------------------------------------------------------------
// Kernel 1: cbuf2[z][kp][b] = h2( Y0*dot(rW2[2kp],f[z,b]), Y0*dot(rW2[2kp+1],f[z,b]) )
// grid (5 bT, 32 z, 5 kQ); 256 thr; each block: 64 b x 10 kp.
// Block (0,0,0) zeroes the 160 group tickets + global ticket (workspace is
// poisoned between iterations); stream order puts this before pair_kernel.
// kQ==0 blocks additionally reduce their f-tile to colsum[z][bT][23].
// ---------------------------------------------------------------------------
__global__ void __launch_bounds__(256) prep_kernel(
    const float* __restrict__ feat,   // [B][286][23]
    const float* __restrict__ rW2,    // [100][23]
    const float* __restrict__ rW1,    // [3][100]
    const float* __restrict__ rb1,    // [100]
    h2v* __restrict__ cbuf2,          // [B][50][320]
    float4* __restrict__ wpk,         // [50]
    float* __restrict__ colsum,       // [B][5][23]
    int* __restrict__ tickets)        // [NGRP + 1]
{
    __shared__ float flds[TB * CIN];          // 5888 B
    __shared__ float csum[8][CIN];            // 736 B
    const int tid = threadIdx.x;
    const int bT  = blockIdx.x;
    const int z   = blockIdx.y;
    const int kQ  = blockIdx.z;

    if (bT == 0 && z == 0 && kQ == 0) {
        if (tid >= 64 && tid < 64 + NGRP + 1) tickets[tid - 64] = 0;
        if (tid < NKP) {
            int k0 = 2 * tid, k1 = k0 + 1;
            F4H u;
            u.h[0] = h2_pack(rW1[k0],           rW1[k1]);
            u.h[1] = h2_pack(rW1[NKH + k0],     rW1[NKH + k1]);
            u.h[2] = h2_pack(rW1[2 * NKH + k0], rW1[2 * NKH + k1]);
            u.h[3] = h2_pack(rb1[k0],           rb1[k1]);
            wpk[tid] = u.f;
        }
    }

    const int b0 = bT * TB;
    const int nf = ((NA - b0 < TB) ? (NA - b0) : TB) * CIN;
    const float* fsrc = feat + ((size_t)z * NA + b0) * CIN;     // contiguous
    for (int i = tid; i < TB * CIN; i += 256)
        flds[i] = (i < nf) ? fsrc[i] : 0.f;
    __syncthreads();

    // register-cache this thread's b-row (b fixed across its kpl iterations)
    const int b = tid & 63;
    float fb[CIN];
    {
        const float* fbp = &flds[b * CIN];
#pragma unroll
        for (int j = 0; j < CIN; ++j) fb[j] = fbp[j];
    }

    if (kQ == 0) {          // uniform branch (blockIdx.z) — barriers safe
        if (tid < 8 * CIN) {
            int j = tid % CIN, ch = tid / CIN;
            float s = 0.f;
#pragma unroll
            for (int bb = 0; bb < 8; ++bb) s += flds[(ch * 8 + bb) * CIN + j];
            csum[ch][j] = s;
        }
        __syncthreads();
        if (tid < CIN) {
            float s = 0.f;
#pragma unroll
            for (int ch = 0; ch < 8; ++ch) s += csum[ch][tid];
            colsum[((size_t)z * NTILE_B + bT) * CIN + tid] = s;
        }
    }

    // kpl = tid>>6 + {0,4,8} — wave-uniform -> rW2 row via scalar path (K$).
    for (int kpl = (tid >> 6); kpl < KQ_SZ; kpl += 4) {
        const int kp = kQ * KQ_SZ + kpl;
        const float* w = rW2 + (size_t)kp * 2 * CIN;   // wave-uniform address
        float s0 = 0.f, s1 = 0.f;
#pragma unroll
        for (int j = 0; j < CIN; ++j) {
            s0 = fmaf(fb[j], w[j], s0);
            s1 = fmaf(fb[j], w[CIN + j], s1);
        }
        cbuf2[((size_t)z * NKP + kp) * NB_PAD + b0 + b] = h2_pack(s0 * Y0F, s1 * Y0F);
    }
}

// ---------------------------------------------------------------------------
// Kernel 2 (fused, last-block-done): grid (24,32,5), all blocks are workers.
// After writing its partials each block fences + takes a two-level ticket
// (per-(z,bT) group counter -> global counter). The block drawing the final
// global ticket runs the head for all 32 z inline (4 passes of 8 z).
// Nobody spins or waits -> deadlock-proof under any dispatch order / replay.
// Head arithmetic replicates the old head_kernel association orders exactly
// (bt-ordered sums, ch-chunked fc1, ordered fc2/fc3) -> bit-identical out.
// Tail LDS = ~10.7 KB -> worker occupancy stays 8 blocks/CU.
// ---------------------------------------------------------------------------
__global__ void __launch_bounds__(256, 8) pair_kernel(
    const float* __restrict__ geom,      // [B][286][3]
    const h2v* __restrict__ cbuf2,       // [B][50][320]
    const float4* __restrict__ wpk,      // [50]
    float* __restrict__ feats_part,      // [5][B][288]
    int* __restrict__ tickets,           // [NGRP + 1]
    const float* __restrict__ colsum,    // [B][5][23]
    const float* __restrict__ rb2,       // [23]
    const float* __restrict__ fc1W, const float* __restrict__ fc1b,
    const float* __restrict__ fc2W, const float* __restrict__ fc2b,
    const float* __restrict__ fc3W, const float* __restrict__ fc3b,
    float* __restrict__ out)             // [B]
{
    __shared__ float ga[ATILE * 3];
    __shared__ int   slast;
    // tail-path scratch (allocated always; 10.6 KB total keeps 8 blocks/CU)
    __shared__ float fsumL[ZG][NA];      // 9152 B
    __shared__ float czsL[ZG];
    __shared__ float h1L[ZG][30];
    __shared__ float hh2L[ZG][10];

    const int tid   = threadIdx.x;
    const int z     = blockIdx.y;
    const int bT    = blockIdx.z;
    const int aBase = blockIdx.x * ATILE;

    if (tid < ATILE * 3) {
        int aa = aBase + tid / 3;
        int d  = tid - 3 * (tid / 3);
        ga[tid] = (aa < NA) ? geom[((size_t)z * NA + aa) * 3 + d] : 0.f;
    }
    __syncthreads();

    const int wave = tid >> 6;
    const int lane = tid & 63;

    const int b = bT * TB + lane;
    float gbx = 0.f, gby = 0.f, gbz = 0.f;
    if (b < NA) {
        const float* g = geom + ((size_t)z * NA + b) * 3;
        gbx = g[0]; gby = g[1]; gbz = g[2];
    }

    // basis, once per (a, b) pair
    h2v u0[APW], u1[APW], u2[APW];
#pragma unroll
    for (int i = 0; i < APW; ++i) {
        float axv = ga[(wave * APW + i) * 3 + 0];
        float ayv = ga[(wave * APW + i) * 3 + 1];
        float azv = ga[(wave * APW + i) * 3 + 2];
        float dx = gbx - axv, dy = gby - ayv, dz = gbz - azv;
        float r  = sqrtf(fmaf(dx, dx, fmaf(dy, dy, fmaf(dz, dz, 1e-12f))));
        float zz = r * (1.f / 1.5f);            // >= 0
        u0[i] = h2_splat(cos_half_pi(fminf(zz, 1.f)));
        u1[i] = h2_splat(cos_half_pi(fminf(fmaxf(zz - 1.f, -1.f), 1.f)));
        u2[i] = h2_splat(cos_half_pi(fminf(fmaxf(zz - 2.f, -1.f), 1.f)));
    }

    float acc[APW] = {0.f, 0.f, 0.f};
    const h2v* cg = cbuf2 + (size_t)z * NKP * NB_PAD + bT * TB + lane;

#pragma unroll 10
    for (int kp = 0; kp < NKP; ++kp) {
        F4H u; u.f = wpk[kp];                // wave-uniform -> s_load_dwordx4
        h2v cb = cg[(size_t)kp * NB_PAD];    // coalesced global b32, L1/L2-hot
#pragma unroll
        for (int i = 0; i < APW; ++i) {
            h2v s = h2_fma(u0[i], u.h[0],
                    h2_fma(u1[i], u.h[1],
                    h2_fma(u2[i], u.h[2], u.h[3])));
            acc[i] = fdot2f(h2_max0(s), cb, acc[i]);
        }
    }

#pragma unroll
    for (int i = 0; i < APW; ++i) {
        float v = acc[i];
        for (int off = 32; off; off >>= 1) v += __shfl_xor(v, off);
        if (lane == 0) {
            int a = aBase + wave * APW + i;
            if (a < NA)
                feats_part[((size_t)bT * BATCH + z) * 288 + a] = v * RSQRT_N;
        }
    }

    // ---- two-level ticket: make partials visible, then count completions ----
    __threadfence();                       // release this block's stores
    __syncthreads();                       // all lanes fenced before ticket
    if (tid == 0) {
        int last = 0;
        int t = atomicAdd(&tickets[z * NTILE_B + bT], 1);
        if (t == NTILE_A - 1)              // group complete
            last = (atomicAdd(&tickets[NGRP], 1) == NGRP - 1);
        slast = last;
    }
    __syncthreads();
    if (!slast) return;

    // ------------------- tail: this is the final block -------------------
    __threadfence();                       // acquire: invalidate L1, see all partials

    for (int zg = 0; zg < BATCH / ZG; ++zg) {
        const int zbase = zg * ZG;

        // fsum[zz][a] = sum_bt featsP (bt in order, as before)
        for (int i = tid; i < ZG * NA; i += 256) {
            int zi = i / NA, a = i - zi * NA;
            int zz = zbase + zi;
            float s = 0.f;
#pragma unroll
            for (int bt = 0; bt < NTILE_B; ++bt)
                s += feats_part[((size_t)bt * BATCH + zz) * 288 + a];
            fsumL[zi][a] = s;
        }
        // czs per z (ps0[j] in j-order, same association as old head)
        if (tid < ZG) {
            int zz = zbase + tid;
            float sacc = 0.f;
            for (int j = 0; j < CIN; ++j) {
                float s = 0.f;
#pragma unroll
                for (int bt = 0; bt < NTILE_B; ++bt)
                    s += colsum[((size_t)zz * NTILE_B + bt) * CIN + j];
                sacc += s * rb2[j];
            }
            czsL[tid] = sacc * (Y0F * RSQRT_N);
        }
        __syncthreads();

        // fc1: (z, j) units; ch-chunked partials summed in ch order (as before)
        if (tid < ZG * 30) {
            int zi = tid / 30, j = tid - zi * 30;
            float o = 0.f, ws = 0.f;
#pragma unroll
            for (int ch = 0; ch < 8; ++ch) {
                int a0 = ch * 36, a1 = (a0 + 36 < NA) ? a0 + 36 : NA;
                float oc = 0.f, wc = 0.f;
                for (int a = a0; a < a1; ++a) {
                    float w = fc1W[a * 30 + j];
                    oc = fmaf(fsumL[zi][a], w, oc);
                    wc += w;
                }
                o += oc; ws += wc;
            }
            h1L[zi][j] = fmaxf(o + czsL[zi] * ws + fc1b[j], 0.f);
        }
        __syncthreads();

        if (tid < ZG * 10) {
            int zi = tid / 10, t = tid - zi * 10;
            float v = fc2b[t];
#pragma unroll
            for (int u = 0; u < 30; ++u) v = fmaf(h1L[zi][u], fc2W[u * 10 + t], v);
            hh2L[zi][t] = fmaxf(v, 0.f);
        }
        __syncthreads();

        if (tid < ZG) {
            float v = fc3b[0];
#pragma unroll
            for (int t = 0; t < 10; ++t) v = fmaf(hh2L[tid][t], fc3W[t], v);
            out[zbase + tid] = v;
        }
        __syncthreads();   // protect fsumL reuse next pass
    }
}

// ---------------------------------------------------------------------------
extern "C" void kernel_launch(void* const* d_in, const int* in_sizes, int n_in,
                              void* d_out, int out_size, void* d_ws, size_t ws_size,
                              hipStream_t stream) {
    const float* features = (const float*)d_in[1];
    const float* geometry = (const float*)d_in[2];
    const float* rW1  = (const float*)d_in[3];
    const float* rb1  = (const float*)d_in[4];
    const float* rW2  = (const float*)d_in[5];
    const float* rb2  = (const float*)d_in[6];
    const float* fc1W = (const float*)d_in[7];
    const float* fc1b = (const float*)d_in[8];
    const float* fc2W = (const float*)d_in[9];
    const float* fc2b = (const float*)d_in[10];
    const float* fc3W = (const float*)d_in[11];
    const float* fc3b = (const float*)d_in[12];

    char* ws = (char*)d_ws;
    float4* wpk    = (float4*)ws;                                    // 800 B
    h2v*    cbuf2  = (h2v*)(ws + 1024);                              // 2.048 MB
    float*  featsP = (float*)(ws + 1024 + (size_t)BATCH * NKP * NB_PAD * 4);
    float*  colsum = featsP + (size_t)NTILE_B * BATCH * 288;         // 32*5*23 f32
    int*    tickets = (int*)(colsum + (size_t)BATCH * NTILE_B * CIN); // [161]

    float* out = (float*)d_out;

    prep_kernel<<<dim3(NTILE_B, BATCH, KQ_N), 256, 0, stream>>>(
        features, rW2, rW1, rb1, cbuf2, wpk, colsum, tickets);
    pair_kernel<<<dim3(NTILE_A, BATCH, NTILE_B), 256, 0, stream>>>(
        geometry, cbuf2, wpk, featsP, tickets, colsum, rb2,
        fc1W, fc1b, fc2W, fc2b, fc3W, fc3b, out);
}

// Round 4
// 121.629 us; speedup vs baseline: 5.9471x; 5.9471x over previous
//
#include <hip/hip_runtime.h>

#define NA      286   // atoms
#define CIN     23
#define NKH     100   // radial hidden width
#define NKP     50    // k-pairs
#define BATCH   32
#define NB_PAD  320
#define TB      64
#define ATILE   12    // a's per block (3 per wave, 4 waves)
#define APW     3
#define NTILE_A 24
#define NTILE_B 5
#define KQ_N    5     // prep kp-groups
#define KQ_SZ   10    // kp per prep block

#define Y0F      0.28209479177387814f   // 1/(2 sqrt(pi))
#define RSQRT_N  0.05913123960994873f   // 1/sqrt(286)

typedef _Float16 h2v __attribute__((ext_vector_type(2)));
union F4H { float4 f; h2v h[4]; };

__device__ __forceinline__ h2v h2_splat(float x) {
    _Float16 v = (_Float16)x;
    h2v r; r.x = v; r.y = v; return r;
}
__device__ __forceinline__ h2v h2_pack(float a, float b) {
    h2v r; r.x = (_Float16)a; r.y = (_Float16)b; return r;
}
__device__ __forceinline__ h2v h2_fma(h2v a, h2v b, h2v c) {
#if __has_builtin(__builtin_elementwise_fma)
    return __builtin_elementwise_fma(a, b, c);
#else
    return a * b + c;
#endif
}
__device__ __forceinline__ h2v h2_max0(h2v a) {
    h2v z; z.x = (_Float16)0.f; z.y = (_Float16)0.f;
#if __has_builtin(__builtin_elementwise_max)
    return __builtin_elementwise_max(a, z);
#else
    h2v r; r.x = a.x > z.x ? a.x : z.x; r.y = a.y > z.y ? a.y : z.y; return r;
#endif
}
__device__ __forceinline__ float fdot2f(h2v a, h2v b, float c) {
#if __has_builtin(__builtin_amdgcn_fdot2)
    return __builtin_amdgcn_fdot2(a, b, c, false);
#else
    return c + (float)a.x * (float)b.x + (float)a.y * (float)b.y;
#endif
}

// cos((pi/2)*x) for |x| <= 1; |err| <= ~3e-5
__device__ __forceinline__ float cos_half_pi(float x) {
    float t = 1.5707963267948966f * x;
    float w = t * t;
    return 1.f + w * (-0.5f + w * (4.16666667e-2f + w * (-1.38888889e-3f
               + w * 2.48015873e-5f)));
}

// ---------------------------------------------------------------------------
// Kernel 1: cbuf2[z][kp][b] = h2( Y0*dot(rW2[2kp],f[z,b]), Y0*dot(rW2[2kp+1],f[z,b]) )
// grid (5 bT, 32 z, 5 kQ); 256 thr; each block: 64 b x 10 kp.
// kQ==0 blocks additionally reduce their f-tile to per-j column sums
// (colsum[z][bT][23]) so the head never touches featIn (strided) again.
// ---------------------------------------------------------------------------
__global__ void __launch_bounds__(256) prep_kernel(
    const float* __restrict__ feat,   // [B][286][23]
    const float* __restrict__ rW2,    // [100][23]
    const float* __restrict__ rW1,    // [3][100]
    const float* __restrict__ rb1,    // [100]
    h2v* __restrict__ cbuf2,          // [B][50][320]
    float4* __restrict__ wpk,         // [50]
    float* __restrict__ colsum)       // [B][5][23]
{
    __shared__ float flds[TB * CIN];          // 5888 B
    __shared__ float wlds[2 * KQ_SZ * CIN];   // 1840 B
    __shared__ float csum[8][CIN];            // 736 B
    const int tid = threadIdx.x;
    const int bT  = blockIdx.x;
    const int z   = blockIdx.y;
    const int kQ  = blockIdx.z;

    if (bT == 0 && z == 0 && kQ == 0 && tid < NKP) {
        int k0 = 2 * tid, k1 = k0 + 1;
        F4H u;
        u.h[0] = h2_pack(rW1[k0],           rW1[k1]);
        u.h[1] = h2_pack(rW1[NKH + k0],     rW1[NKH + k1]);
        u.h[2] = h2_pack(rW1[2 * NKH + k0], rW1[2 * NKH + k1]);
        u.h[3] = h2_pack(rb1[k0],           rb1[k1]);
        wpk[tid] = u.f;
    }

    const int b0 = bT * TB;
    const int nf = ((NA - b0 < TB) ? (NA - b0) : TB) * CIN;
    const float* fsrc = feat + ((size_t)z * NA + b0) * CIN;     // contiguous
    for (int i = tid; i < TB * CIN; i += 256)
        flds[i] = (i < nf) ? fsrc[i] : 0.f;
    const float* wsrc = rW2 + (size_t)kQ * KQ_SZ * 2 * CIN;     // contiguous
    for (int i = tid; i < 2 * KQ_SZ * CIN; i += 256)
        wlds[i] = wsrc[i];
    __syncthreads();

    if (kQ == 0) {          // uniform branch (blockIdx.z) — barriers safe
        if (tid < 8 * CIN) {
            int j = tid % CIN, ch = tid / CIN;
            float s = 0.f;
#pragma unroll
            for (int bb = 0; bb < 8; ++bb) s += flds[(ch * 8 + bb) * CIN + j];
            csum[ch][j] = s;
        }
        __syncthreads();
        if (tid < CIN) {
            float s = 0.f;
#pragma unroll
            for (int ch = 0; ch < 8; ++ch) s += csum[ch][tid];
            colsum[((size_t)z * NTILE_B + bT) * CIN + tid] = s;
        }
    }

    for (int i = tid; i < TB * KQ_SZ; i += 256) {
        int b   = i & 63;
        int kpl = i >> 6;               // wave-uniform per iteration
        const float* w0 = &wlds[(2 * kpl) * CIN];
        const float* w1 = &wlds[(2 * kpl + 1) * CIN];
        const float* fb = &flds[b * CIN];
        float s0 = 0.f, s1 = 0.f;
#pragma unroll
        for (int j = 0; j < CIN; ++j) {
            s0 = fmaf(fb[j], w0[j], s0);
            s1 = fmaf(fb[j], w1[j], s1);
        }
        int kp = kQ * KQ_SZ + kpl;
        cbuf2[((size_t)z * NKP + kp) * NB_PAD + b0 + b] = h2_pack(s0 * Y0F, s1 * Y0F);
    }
}

// ---------------------------------------------------------------------------
// Kernel 2: partial[bT][z][a] = sum_{b in tile} sum_kp dot2(relu(u@W), c)
// grid (24 aT, 32 z, 5 bT) = 3840 blocks = 15/CU -> 32 waves/CU resident.
// Stage c[50 kp][64 b] (12.8 KB) + W (800 B) to LDS once; pure-DS k-loop:
// per kp = 1 uniform ds_read_b128 (broadcast) + 1 stride-1 ds_read_b32 + 15 VALU.
// Basis computed ONCE per (a,b). __launch_bounds__(256,8): VGPR<=64.
// [best measured this session: 120.74 µs, absmax 0.0, 44 VGPR]
// ---------------------------------------------------------------------------
__global__ void __launch_bounds__(256, 8) pair_kernel(
    const float* __restrict__ geom,      // [B][286][3]
    const h2v* __restrict__ cbuf2,       // [B][50][320]
    const float4* __restrict__ wpk,      // [50]
    float* __restrict__ feats_part)      // [5][B][288]
{
    __shared__ h2v    c_lds[NKP * TB];   // 12800 B
    __shared__ float4 w_lds[NKP];        // 800 B
    __shared__ float  ga[ATILE * 3];

    const int tid   = threadIdx.x;
    const int z     = blockIdx.y;
    const int bT    = blockIdx.z;
    const int aBase = blockIdx.x * ATILE;

    // ---- stage: c-tile (50 rows x 16 uint4, coalesced) + W + a-geom ----
    {
        const uint4* s4 = (const uint4*)(cbuf2 + (size_t)z * NKP * NB_PAD + bT * TB);
        uint4*       d4 = (uint4*)c_lds;
#pragma unroll
        for (int r = 0; r < 4; ++r) {        // 800 uint4 over 256 thr
            int i = r * 256 + tid;
            if (i < NKP * 16) {
                int row = i >> 4, col = i & 15;
                d4[i] = s4[(size_t)row * (NB_PAD / 4) + col];
            }
        }
    }
    if (tid < NKP) ((uint4*)w_lds)[tid] = ((const uint4*)wpk)[tid];
    if (tid >= 128 && tid < 128 + ATILE * 3) {
        int t  = tid - 128;
        int aa = aBase + t / 3;
        int d  = t - 3 * (t / 3);
        ga[t] = (aa < NA) ? geom[((size_t)z * NA + aa) * 3 + d] : 0.f;
    }
    __syncthreads();

    const int wave = tid >> 6;
    const int lane = tid & 63;

    const int b = bT * TB + lane;
    float gbx = 0.f, gby = 0.f, gbz = 0.f;
    if (b < NA) {
        const float* g = geom + ((size_t)z * NA + b) * 3;
        gbx = g[0]; gby = g[1]; gbz = g[2];
    }

    // basis, once per (a, b) pair
    h2v u0[APW], u1[APW], u2[APW];
#pragma unroll
    for (int i = 0; i < APW; ++i) {
        float axv = ga[(wave * APW + i) * 3 + 0];
        float ayv = ga[(wave * APW + i) * 3 + 1];
        float azv = ga[(wave * APW + i) * 3 + 2];
        float dx = gbx - axv, dy = gby - ayv, dz = gbz - azv;
        float r  = sqrtf(fmaf(dx, dx, fmaf(dy, dy, fmaf(dz, dz, 1e-12f))));
        float zz = r * (1.f / 1.5f);            // >= 0
        u0[i] = h2_splat(cos_half_pi(fminf(zz, 1.f)));
        u1[i] = h2_splat(cos_half_pi(fminf(fmaxf(zz - 1.f, -1.f), 1.f)));
        u2[i] = h2_splat(cos_half_pi(fminf(fmaxf(zz - 2.f, -1.f), 1.f)));
    }

    float acc[APW] = {0.f, 0.f, 0.f};
    const h2v* cl = c_lds + lane;

#pragma unroll 10
    for (int kp = 0; kp < NKP; ++kp) {
        F4H u; u.f = w_lds[kp];          // uniform addr -> broadcast, no conflict
        h2v cb = cl[kp * TB];            // stride-1 over lanes, conflict-free
#pragma unroll
        for (int i = 0; i < APW; ++i) {
            h2v s = h2_fma(u0[i], u.h[0],
                    h2_fma(u1[i], u.h[1],
                    h2_fma(u2[i], u.h[2], u.h[3])));
            acc[i] = fdot2f(h2_max0(s), cb, acc[i]);
        }
    }

#pragma unroll
    for (int i = 0; i < APW; ++i) {
        float v = acc[i];
        for (int off = 32; off; off >>= 1) v += __shfl_xor(v, off);
        if (lane == 0) {
            int a = aBase + wave * APW + i;
            if (a < NA)
                feats_part[((size_t)bT * BATCH + z) * 288 + a] = v * RSQRT_N;
        }
    }
}

// ---------------------------------------------------------------------------
// Kernel 3: head, 256 thr per z. Sums 5 b-tile partials; cz from precomputed
// colsum (115 contiguous floats) instead of a strided featIn pass:
//   h1[j] = relu( sum_a fs[a]*W[a,j] + cz * sum_a W[a,j] + b[j] )
// ---------------------------------------------------------------------------
__global__ void __launch_bounds__(256) head_kernel(
    const float* __restrict__ featsP,   // [5][B][288]
    const float* __restrict__ colsum,   // [B][5][23]
    const float* __restrict__ rb2,      // [23]
    const float* __restrict__ fc1W, const float* __restrict__ fc1b,
    const float* __restrict__ fc2W, const float* __restrict__ fc2b,
    const float* __restrict__ fc3W, const float* __restrict__ fc3b,
    float* __restrict__ out)            // [B]
{
    __shared__ float fsum[NA];
    __shared__ float ps0[CIN];
    __shared__ float po[8][30], pw[8][30];
    __shared__ float czs;
    __shared__ float h1[30], hh2[10];

    const int z = blockIdx.x, tid = threadIdx.x;

    for (int a = tid; a < NA; a += 256) {
        float s = 0.f;
#pragma unroll
        for (int bt = 0; bt < NTILE_B; ++bt)
            s += featsP[((size_t)bt * BATCH + z) * 288 + a];
        fsum[a] = s;
    }

    if (tid < CIN) {
        float s = 0.f;
#pragma unroll
        for (int bt = 0; bt < NTILE_B; ++bt)
            s += colsum[((size_t)z * NTILE_B + bt) * CIN + tid];
        ps0[tid] = s * rb2[tid];
    }
    __syncthreads();
    if (tid == 0) {
        float s = 0.f;
#pragma unroll
        for (int j = 0; j < CIN; ++j) s += ps0[j];
        czs = s * (Y0F * RSQRT_N);
    }

    // fc1 partials: 8 a-chunks x 30 outputs
    if (tid < 240) {
        int j = tid % 30, ch = tid / 30;
        int a0 = ch * 36, a1 = (a0 + 36 < NA) ? a0 + 36 : NA;
        float o = 0.f, ws = 0.f;
#pragma unroll 4
        for (int a = a0; a < a1; ++a) {
            float w = fc1W[a * 30 + j];
            o  = fmaf(fsum[a], w, o);
            ws += w;
        }
        po[ch][j] = o; pw[ch][j] = ws;
    }
    __syncthreads();
    if (tid < 30) {
        float o = 0.f, ws = 0.f;
#pragma unroll
        for (int ch = 0; ch < 8; ++ch) { o += po[ch][tid]; ws += pw[ch][tid]; }
        h1[tid] = fmaxf(o + czs * ws + fc1b[tid], 0.f);
    }
    __syncthreads();
    if (tid < 10) {
        float v = fc2b[tid];
#pragma unroll
        for (int t = 0; t < 30; ++t) v = fmaf(h1[t], fc2W[t * 10 + tid], v);
        hh2[tid] = fmaxf(v, 0.f);
    }
    __syncthreads();
    if (tid == 0) {
        float v = fc3b[0];
#pragma unroll
        for (int t = 0; t < 10; ++t) v = fmaf(hh2[t], fc3W[t], v);
        out[z] = v;
    }
}

// ---------------------------------------------------------------------------
extern "C" void kernel_launch(void* const* d_in, const int* in_sizes, int n_in,
                              void* d_out, int out_size, void* d_ws, size_t ws_size,
                              hipStream_t stream) {
    const float* features = (const float*)d_in[1];
    const float* geometry = (const float*)d_in[2];
    const float* rW1  = (const float*)d_in[3];
    const float* rb1  = (const float*)d_in[4];
    const float* rW2  = (const float*)d_in[5];
    const float* rb2  = (const float*)d_in[6];
    const float* fc1W = (const float*)d_in[7];
    const float* fc1b = (const float*)d_in[8];
    const float* fc2W = (const float*)d_in[9];
    const float* fc2b = (const float*)d_in[10];
    const float* fc3W = (const float*)d_in[11];
    const float* fc3b = (const float*)d_in[12];

    char* ws = (char*)d_ws;
    float4* wpk    = (float4*)ws;                                    // 800 B
    h2v*    cbuf2  = (h2v*)(ws + 1024);                              // 2.048 MB
    float*  featsP = (float*)(ws + 1024 + (size_t)BATCH * NKP * NB_PAD * 4);
    float*  colsum = featsP + (size_t)NTILE_B * BATCH * 288;         // 32*5*23 f32

    float* out = (float*)d_out;

    prep_kernel<<<dim3(NTILE_B, BATCH, KQ_N), 256, 0, stream>>>(
        features, rW2, rW1, rb1, cbuf2, wpk, colsum);
    pair_kernel<<<dim3(NTILE_A, BATCH, NTILE_B), 256, 0, stream>>>(
        geometry, cbuf2, wpk, featsP);
    head_kernel<<<BATCH, 256, 0, stream>>>(
        featsP, colsum, rb2, fc1W, fc1b, fc2W, fc2b, fc3W, fc3b, out);
}